// Round 6
// baseline (4382.031 us; speedup 1.0000x reference)
//
#include <hip/hip_runtime.h>

constexpr int B = 512, T = 128, F = 128, H = 256;

// ---------------------------------------------------------------------------
// Kernel 1: x_score[b,f] = sum_t x[b,t,f] * w_x[t]; a = softmax_f(x_score);
// write a to ws and replicate into attns output for all t.
// (softmax over f is invariant to the per-row scalar (h.w_h + c.w_c + attn_b),
//  so the attention map is identical at every timestep. VERIFIED on HW r4:
//  output 0 passed.)
// ---------------------------------------------------------------------------
__global__ void __launch_bounds__(128)
attn_softmax_kernel(const float* __restrict__ x,
                    const float* __restrict__ attn_w,
                    float* __restrict__ a_ws,
                    float* __restrict__ attns_out) {
  const int b = blockIdx.x;
  const int f = threadIdx.x;  // 128 threads
  const float* __restrict__ wx = attn_w + 2 * H;  // w_x, length T
  const float* xb = x + (size_t)b * T * F + f;
  float acc = 0.f;
#pragma unroll 8
  for (int t = 0; t < T; ++t) acc = fmaf(xb[(size_t)t * F], wx[t], acc);

  // block softmax over 128 values (2 waves)
  float m = acc;
#pragma unroll
  for (int i = 1; i < 64; i <<= 1) m = fmaxf(m, __shfl_xor(m, i));
  __shared__ float sred[2];
  __shared__ float ssum[2];
  __shared__ float arow[128];
  const int wid = f >> 6;
  if ((f & 63) == 0) sred[wid] = m;
  __syncthreads();
  m = fmaxf(sred[0], sred[1]);
  const float e = expf(acc - m);
  float s = e;
#pragma unroll
  for (int i = 1; i < 64; i <<= 1) s += __shfl_xor(s, i);
  if ((f & 63) == 0) ssum[wid] = s;
  __syncthreads();
  s = ssum[0] + ssum[1];
  const float av = e / s;
  a_ws[(size_t)b * F + f] = av;
  arow[f] = av;
  __syncthreads();

  // replicate a over all t, vectorized float4 writes
  const int c4 = f & 31;  // float4 column 0..31
  float4 a4 = *(const float4*)&arow[c4 << 2];
  float4* ob = (float4*)(attns_out + (size_t)b * T * F);
  for (int t = f >> 5; t < T; t += 4) {
    ob[t * 32 + c4] = a4;
  }
}

// ---------------------------------------------------------------------------
// Kernel 2: persistent LSTM, per-btile barrier (16 WGs), NO grid sync.
// Grid: 512 WGs (32 btiles x 16 ntiles), 256 threads.
// Static LDS = 24.5 KB (w_ih streamed from L2, not LDS-staged) so the
// cooperative-launch occupancy check passes; r4 failure diagnosed as
// CooperativeLaunchTooLarge with 57.5 KB LDS -> kernel never ran, enc==0
// (absmax 0.1035 == max|enc_ref|). Fallback: plain launch if coop launch
// errors (kernel has no grid.sync; at 24.5 KB LDS / 128 VGPR cap, 4
// blocks/CU => 1024 slots >= 512 WGs co-resident).
//
// WG owns 16 batches x 16 h-cols; thread owns one (b,n) and all 4 gates, so
// c stays in a register. Step order hides barrier + h-exchange latency behind
// the h-independent partial GEMM:
//   A: stage wi_t = a*x_t (LDS)                          [no h dep]
//   B: acc = bias + wi . w_ih^T (K=128, w_ih streamed)   [no h dep]
//   C: wait btile barrier (h_{t-1} ready; agent acquire fence)
//   D: stage h_{t-1} (LDS)
//   E: acc += h . w_hh^T (K=256, streamed); gates; stores
//   F: agent-scope release atomicAdd signal
// Race-freedom: hbuf[p] readers at step t+1 ordered after step-t writers by
// the acquire/release counter; step-t+2 writers ordered after step-t+1's
// barrier wait (which requires every WG's step-t+1 reads to have completed)
// -> no WAR overlap. Cross-XCD visibility via agent-scope release/acquire
// (compiler emits L2 writeback/invalidate per the gfx9xx memory model);
// btile=wg&31 additionally keeps each btile's 16 WGs on one XCD under
// round-robin dispatch so the exchange is usually XCD-local.
// ---------------------------------------------------------------------------
constexpr int WI_LD  = 132;  // 128+4: rows shift 4 banks -> <=2-way (free)
constexpr int HS_LD  = 260;  // 256+4: same

__global__ void __launch_bounds__(256, 4)
lstm_kernel(const float* __restrict__ x,      // (B,T,F)
            const float* __restrict__ w_ih,   // (4H,F)
            const float* __restrict__ w_hh,   // (4H,H)
            const float* __restrict__ b_ih,   // (4H)
            const float* __restrict__ b_hh,   // (4H)
            const float* __restrict__ h0,     // (B,H)
            const float* __restrict__ c0,     // (B,H)
            const float* __restrict__ a_ws,   // (B,F)
            float* __restrict__ hbuf,         // (2,B,H) ws
            float* __restrict__ enc_out,      // (B,T,H)
            unsigned int* __restrict__ bar) { // 32 counters, 256B apart
  const int wg = blockIdx.x;
  const int btile = wg & 31;   // all 16 WGs of a btile share XCD btile%8
  const int ntile = wg >> 5;
  const int b0 = btile * 16;
  const int n0 = ntile * 16;
  const int tid = threadIdx.x;
  const int nl = tid >> 4;     // h-col within tile (uniform per 16 lanes ->
  const int lb = tid & 15;     //   4 unique weight segments per wave load)
  const int b = b0 + lb;
  const int n = n0 + nl;

  __shared__ __align__(16) float wi_s[16][WI_LD];    //  8.4 KB
  __shared__ __align__(16) float hs_s[16][HS_LD];    // 16.6 KB (24.5 KB tot)

  const float bias0 = b_ih[0 * H + n] + b_hh[0 * H + n];
  const float bias1 = b_ih[1 * H + n] + b_hh[1 * H + n];
  const float bias2 = b_ih[2 * H + n] + b_hh[2 * H + n];
  const float bias3 = b_ih[3 * H + n] + b_hh[3 * H + n];
  float c = c0[(size_t)b * H + n];

  const float* __restrict__ wr0 = w_ih + (size_t)(0 * H + n) * F;
  const float* __restrict__ wr1 = w_ih + (size_t)(1 * H + n) * F;
  const float* __restrict__ wr2 = w_ih + (size_t)(2 * H + n) * F;
  const float* __restrict__ wr3 = w_ih + (size_t)(3 * H + n) * F;
  const float* __restrict__ hr0 = w_hh + (size_t)(0 * H + n) * H;
  const float* __restrict__ hr1 = w_hh + (size_t)(1 * H + n) * H;
  const float* __restrict__ hr2 = w_hh + (size_t)(2 * H + n) * H;
  const float* __restrict__ hr3 = w_hh + (size_t)(3 * H + n) * H;

  // fixed staging slots for wi: thread stages rows r0 and r0+8
  const int r0 = tid >> 5;             // 0..7
  const int cA = (tid & 31) << 2;      // float4 col
  const int r1 = r0 + 8;
  const float4 aA = *(const float4*)(a_ws + (size_t)(b0 + r0) * F + cA);
  const float4 aB = *(const float4*)(a_ws + (size_t)(b0 + r1) * F + cA);

  unsigned int* bcnt = bar + btile * 64;  // 256B-padded counters

  for (int t = 0; t < T; ++t) {
    // ---- A: stage wi_t ----
    {
      const float4 xA = *(const float4*)(x + ((size_t)(b0 + r0) * T + t) * F + cA);
      const float4 xB = *(const float4*)(x + ((size_t)(b0 + r1) * T + t) * F + cA);
      float4 wA, wB;
      wA.x = aA.x * xA.x; wA.y = aA.y * xA.y; wA.z = aA.z * xA.z; wA.w = aA.w * xA.w;
      wB.x = aB.x * xB.x; wB.y = aB.y * xB.y; wB.z = aB.z * xB.z; wB.w = aB.w * xB.w;
      *(float4*)&wi_s[r0][cA] = wA;
      *(float4*)&wi_s[r1][cA] = wB;
    }
    __syncthreads();

    // ---- B: h-independent partial (K=128, w_ih streamed L1/L2) ----
    float acc0 = bias0, acc1 = bias1, acc2 = bias2, acc3 = bias3;
#pragma unroll 4
    for (int k = 0; k < F; k += 4) {
      const float4 xv = *(const float4*)&wi_s[lb][k];
      const float4 w0 = *(const float4*)(wr0 + k);
      const float4 w1 = *(const float4*)(wr1 + k);
      const float4 w2 = *(const float4*)(wr2 + k);
      const float4 w3 = *(const float4*)(wr3 + k);
      acc0 = fmaf(xv.x, w0.x, fmaf(xv.y, w0.y, fmaf(xv.z, w0.z, fmaf(xv.w, w0.w, acc0))));
      acc1 = fmaf(xv.x, w1.x, fmaf(xv.y, w1.y, fmaf(xv.z, w1.z, fmaf(xv.w, w1.w, acc1))));
      acc2 = fmaf(xv.x, w2.x, fmaf(xv.y, w2.y, fmaf(xv.z, w2.z, fmaf(xv.w, w2.w, acc2))));
      acc3 = fmaf(xv.x, w3.x, fmaf(xv.y, w3.y, fmaf(xv.z, w3.z, fmaf(xv.w, w3.w, acc3))));
    }

    // ---- C: wait for h_{t-1} from the 16 WGs of this btile ----
    if (tid == 0) {
      const unsigned int target = 16u * (unsigned int)t;
      while (__hip_atomic_load(bcnt, __ATOMIC_RELAXED,
                               __HIP_MEMORY_SCOPE_AGENT) < target) { }
      __builtin_amdgcn_fence(__ATOMIC_ACQUIRE, "agent");
    }
    __syncthreads();

    // ---- D: stage h_{t-1} ----
    const float* __restrict__ hprev =
        (t == 0) ? h0 : (hbuf + (size_t)((t - 1) & 1) * B * H);
#pragma unroll
    for (int i = 0; i < 4; ++i) {
      const int j = tid + (i << 8);
      const int r = j >> 6;
      const int cc = (j & 63) << 2;
      *(float4*)&hs_s[r][cc] = *(const float4*)(hprev + (size_t)(b0 + r) * H + cc);
    }
    __syncthreads();

    // ---- E: recurrent part (K=256, w_hh streamed from L1/L2) ----
#pragma unroll 4
    for (int k = 0; k < H; k += 4) {
      const float4 xv = *(const float4*)&hs_s[lb][k];
      const float4 w0 = *(const float4*)(hr0 + k);
      const float4 w1 = *(const float4*)(hr1 + k);
      const float4 w2 = *(const float4*)(hr2 + k);
      const float4 w3 = *(const float4*)(hr3 + k);
      acc0 = fmaf(xv.x, w0.x, fmaf(xv.y, w0.y, fmaf(xv.z, w0.z, fmaf(xv.w, w0.w, acc0))));
      acc1 = fmaf(xv.x, w1.x, fmaf(xv.y, w1.y, fmaf(xv.z, w1.z, fmaf(xv.w, w1.w, acc1))));
      acc2 = fmaf(xv.x, w2.x, fmaf(xv.y, w2.y, fmaf(xv.z, w2.z, fmaf(xv.w, w2.w, acc2))));
      acc3 = fmaf(xv.x, w3.x, fmaf(xv.y, w3.y, fmaf(xv.z, w3.z, fmaf(xv.w, w3.w, acc3))));
    }

    const float si = 1.f / (1.f + expf(-acc0));
    const float sf = 1.f / (1.f + expf(-acc1));
    const float tg = tanhf(acc2);
    const float so = 1.f / (1.f + expf(-acc3));
    const float cn = sf * c + si * tg;
    const float hn = so * tanhf(cn);
    c = cn;

    hbuf[(size_t)(t & 1) * B * H + (size_t)b * H + n] = hn;
    enc_out[((size_t)b * T + t) * H + n] = hn;
    __syncthreads();  // all WG stores retired before signalling

    // ---- F: release-signal ----
    if (tid == 0) {
      __hip_atomic_fetch_add(bcnt, 1u, __ATOMIC_RELEASE,
                             __HIP_MEMORY_SCOPE_AGENT);
    }
  }
}

// ---------------------------------------------------------------------------
extern "C" void kernel_launch(void* const* d_in, const int* in_sizes, int n_in,
                              void* d_out, int out_size, void* d_ws, size_t ws_size,
                              hipStream_t stream) {
  (void)in_sizes; (void)n_in; (void)out_size; (void)ws_size;
  const float* x      = (const float*)d_in[0];
  const float* attn_w = (const float*)d_in[1];
  // d_in[2] (attn_b) provably cancels in the softmax -> unused
  const float* w_ih   = (const float*)d_in[3];
  const float* w_hh   = (const float*)d_in[4];
  const float* b_ih   = (const float*)d_in[5];
  const float* b_hh   = (const float*)d_in[6];
  const float* h0     = (const float*)d_in[7];
  const float* c0     = (const float*)d_in[8];

  float* out   = (float*)d_out;
  float* attns = out;                           // (B,T,F)
  float* enc   = out + (size_t)B * T * F;       // (B,T,H)

  unsigned int* bar = (unsigned int*)d_ws;      // 32 x 64 uints (8KB)
  float* a_ws = (float*)d_ws + 2048;            // (B,F)
  float* hbuf = a_ws + (size_t)B * F;           // (2,B,H)

  hipMemsetAsync(bar, 0, 2048 * sizeof(unsigned int), stream);

  attn_softmax_kernel<<<dim3(B), dim3(128), 0, stream>>>(x, attn_w, a_ws, attns);

  void* args[] = { (void*)&x, (void*)&w_ih, (void*)&w_hh, (void*)&b_ih,
                   (void*)&b_hh, (void*)&h0, (void*)&c0, (void*)&a_ws,
                   (void*)&hbuf, (void*)&enc, (void*)&bar };
  hipError_t st = hipLaunchCooperativeKernel((void*)lstm_kernel, dim3(512),
                                             dim3(256), args, 0, stream);
  if (st != hipSuccess) {
    // coop rejection (occupancy validation or graph-capture) -> plain launch;
    // kernel has no grid.sync and all 512 WGs are co-resident at 4 blocks/CU.
    (void)hipGetLastError();  // clear sticky error
    lstm_kernel<<<dim3(512), dim3(256), 0, stream>>>(
        x, w_ih, w_hh, b_ih, b_hh, h0, c0, a_ws, hbuf, enc, bar);
  }
}

// Round 8
// 3491.954 us; speedup vs baseline: 1.2549x; 1.2549x over previous
//
#include <hip/hip_runtime.h>

constexpr int B = 512, T = 128, F = 128, H = 256;

// ---------------------------------------------------------------------------
// Kernel 1: x_score[b,f] = sum_t x[b,t,f] * w_x[t]; a = softmax_f(x_score);
// write a to ws and replicate into attns output for all t.
// (softmax over f is invariant to the per-row scalar (h.w_h + c.w_c + attn_b),
//  so the attention map is identical at every timestep. VERIFIED on HW r4/r6.)
// ---------------------------------------------------------------------------
__global__ void __launch_bounds__(128)
attn_softmax_kernel(const float* __restrict__ x,
                    const float* __restrict__ attn_w,
                    float* __restrict__ a_ws,
                    float* __restrict__ attns_out) {
  const int b = blockIdx.x;
  const int f = threadIdx.x;  // 128 threads
  const float* __restrict__ wx = attn_w + 2 * H;  // w_x, length T
  const float* xb = x + (size_t)b * T * F + f;
  float acc = 0.f;
#pragma unroll 8
  for (int t = 0; t < T; ++t) acc = fmaf(xb[(size_t)t * F], wx[t], acc);

  // block softmax over 128 values (2 waves)
  float m = acc;
#pragma unroll
  for (int i = 1; i < 64; i <<= 1) m = fmaxf(m, __shfl_xor(m, i));
  __shared__ float sred[2];
  __shared__ float ssum[2];
  __shared__ float arow[128];
  const int wid = f >> 6;
  if ((f & 63) == 0) sred[wid] = m;
  __syncthreads();
  m = fmaxf(sred[0], sred[1]);
  const float e = expf(acc - m);
  float s = e;
#pragma unroll
  for (int i = 1; i < 64; i <<= 1) s += __shfl_xor(s, i);
  if ((f & 63) == 0) ssum[wid] = s;
  __syncthreads();
  s = ssum[0] + ssum[1];
  const float av = e / s;
  a_ws[(size_t)b * F + f] = av;
  arow[f] = av;
  __syncthreads();

  // replicate a over all t, vectorized float4 writes
  const int c4 = f & 31;  // float4 column 0..31
  float4 a4 = *(const float4*)&arow[c4 << 2];
  float4* ob = (float4*)(attns_out + (size_t)b * T * F);
  for (int t = f >> 5; t < T; t += 4) {
    ob[t * 32 + c4] = a4;
  }
}

// ---------------------------------------------------------------------------
// Kernel 2: persistent LSTM. r6 measured: 34.4 us/step, VALUBusy 23%,
// FETCH 26.5 MB (L2 warm -> reads healthy), WRITE 221 MB (hbuf forced out
// every step) => the agent-scope RELEASE fetch_add + ACQUIRE fence barrier
// (16 serialized L3 RMWs on one hot line per btile/step + 16 spinners on the
// same line + per-step cache maintenance) was ~77% of the time.
//
// This round: FENCE-FREE flag barrier.
//  - Each WG publishes its step number to its OWN 256B-padded flag with a
//    RELAXED agent atomic store (no RMW, no fence). __syncthreads() before it
//    compiles with s_waitcnt vmcnt(0), so this WG's h atomic stores are
//    ACK'd at the coherence point before the flag store issues ->
//    flag-after-data without any cache-wide maintenance.
//  - Consumers: lanes 0..15 poll the btile's 16 flags with ONE wave-level
//    relaxed atomic load per iteration (exec-mask loop waits for slowest).
//  - h exchange: relaxed agent atomic stores (1 float/thread) + 8B relaxed
//    agent atomic loads -> coherent through LLC, no stale L1/L2, placement-
//    independent.
// Race-freedom: consumer step t waits flags>=t (partners finished t-1, their
// h at coherence point). hbuf[p] rewritten at t+2 only after flags>=t+2 (all
// partner D-reads of p at t+1 done) -> double-buffer WAR safe. t=0 reads h0;
// flags zeroed by memset each launch.
//
// Step order (hides publish/poll behind h-independent work):
//   A: stage wi_t = a*x_t (LDS)                          [no h dep]
//   B: acc = bias + wi . w_ih^T (K=128, streamed)        [no h dep]
//   C: poll 16 flags >= t; __syncthreads
//   D: stage h_{t-1} (8B relaxed atomic loads -> LDS)
//   E: acc += h . w_hh^T (K=256, streamed); gates; enc store; h atomic store
//   F: __syncthreads (vmcnt0) + flag := t+1 (relaxed atomic store)
// ---------------------------------------------------------------------------
constexpr int WI_LD  = 132;  // 128+4: rows shift 4 banks -> <=2-way (free)
constexpr int HS_LD  = 260;  // 256+4: same

__global__ void __launch_bounds__(256, 4)
lstm_kernel(const float* __restrict__ x,      // (B,T,F)
            const float* __restrict__ w_ih,   // (4H,F)
            const float* __restrict__ w_hh,   // (4H,H)
            const float* __restrict__ b_ih,   // (4H)
            const float* __restrict__ b_hh,   // (4H)
            const float* __restrict__ h0,     // (B,H)
            const float* __restrict__ c0,     // (B,H)
            const float* __restrict__ a_ws,   // (B,F)
            float* __restrict__ hbuf,         // (2,B,H) ws
            float* __restrict__ enc_out,      // (B,T,H)
            unsigned int* __restrict__ flags) { // 512 flags, 256B apart
  const int wg = blockIdx.x;
  const int btile = wg & 31;   // all 16 WGs of a btile share XCD btile%8
  const int ntile = wg >> 5;
  const int b0 = btile * 16;
  const int n0 = ntile * 16;
  const int tid = threadIdx.x;
  const int nl = tid >> 4;     // h-col within tile (uniform per 16 lanes ->
  const int lb = tid & 15;     //   4 unique weight segments per wave load)
  const int b = b0 + lb;
  const int n = n0 + nl;

  __shared__ __align__(16) float wi_s[16][WI_LD];    //  8.4 KB
  __shared__ __align__(16) float hs_s[16][HS_LD];    // 16.6 KB (24.5 KB tot)

  const float bias0 = b_ih[0 * H + n] + b_hh[0 * H + n];
  const float bias1 = b_ih[1 * H + n] + b_hh[1 * H + n];
  const float bias2 = b_ih[2 * H + n] + b_hh[2 * H + n];
  const float bias3 = b_ih[3 * H + n] + b_hh[3 * H + n];
  float c = c0[(size_t)b * H + n];

  const float* __restrict__ wr0 = w_ih + (size_t)(0 * H + n) * F;
  const float* __restrict__ wr1 = w_ih + (size_t)(1 * H + n) * F;
  const float* __restrict__ wr2 = w_ih + (size_t)(2 * H + n) * F;
  const float* __restrict__ wr3 = w_ih + (size_t)(3 * H + n) * F;
  const float* __restrict__ hr0 = w_hh + (size_t)(0 * H + n) * H;
  const float* __restrict__ hr1 = w_hh + (size_t)(1 * H + n) * H;
  const float* __restrict__ hr2 = w_hh + (size_t)(2 * H + n) * H;
  const float* __restrict__ hr3 = w_hh + (size_t)(3 * H + n) * H;

  // fixed staging slots for wi: thread stages rows r0 and r0+8
  const int r0 = tid >> 5;             // 0..7
  const int cA = (tid & 31) << 2;      // float4 col
  const int r1 = r0 + 8;
  const float4 aA = *(const float4*)(a_ws + (size_t)(b0 + r0) * F + cA);
  const float4 aB = *(const float4*)(a_ws + (size_t)(b0 + r1) * F + cA);

  unsigned int* myflag   = flags + (size_t)(btile * 16 + ntile) * 64;
  unsigned int* pollflag = flags + (size_t)(btile * 16 + (tid & 15)) * 64;

  for (int t = 0; t < T; ++t) {
    // ---- A: stage wi_t ----
    {
      const float4 xA = *(const float4*)(x + ((size_t)(b0 + r0) * T + t) * F + cA);
      const float4 xB = *(const float4*)(x + ((size_t)(b0 + r1) * T + t) * F + cA);
      float4 wA, wB;
      wA.x = aA.x * xA.x; wA.y = aA.y * xA.y; wA.z = aA.z * xA.z; wA.w = aA.w * xA.w;
      wB.x = aB.x * xB.x; wB.y = aB.y * xB.y; wB.z = aB.z * xB.z; wB.w = aB.w * xB.w;
      *(float4*)&wi_s[r0][cA] = wA;
      *(float4*)&wi_s[r1][cA] = wB;
    }
    __syncthreads();

    // ---- B: h-independent partial (K=128, w_ih streamed L1/L2) ----
    float acc0 = bias0, acc1 = bias1, acc2 = bias2, acc3 = bias3;
#pragma unroll 4
    for (int k = 0; k < F; k += 4) {
      const float4 xv = *(const float4*)&wi_s[lb][k];
      const float4 w0 = *(const float4*)(wr0 + k);
      const float4 w1 = *(const float4*)(wr1 + k);
      const float4 w2 = *(const float4*)(wr2 + k);
      const float4 w3 = *(const float4*)(wr3 + k);
      acc0 = fmaf(xv.x, w0.x, fmaf(xv.y, w0.y, fmaf(xv.z, w0.z, fmaf(xv.w, w0.w, acc0))));
      acc1 = fmaf(xv.x, w1.x, fmaf(xv.y, w1.y, fmaf(xv.z, w1.z, fmaf(xv.w, w1.w, acc1))));
      acc2 = fmaf(xv.x, w2.x, fmaf(xv.y, w2.y, fmaf(xv.z, w2.z, fmaf(xv.w, w2.w, acc2))));
      acc3 = fmaf(xv.x, w3.x, fmaf(xv.y, w3.y, fmaf(xv.z, w3.z, fmaf(xv.w, w3.w, acc3))));
    }

    // ---- C: wait until the 16 WGs of this btile finished step t-1 ----
    if (tid < 16) {
      const unsigned int target = (unsigned int)t;
      while (__hip_atomic_load(pollflag, __ATOMIC_RELAXED,
                               __HIP_MEMORY_SCOPE_AGENT) < target) { }
    }
    __syncthreads();

    // ---- D: stage h_{t-1} via 8B relaxed agent atomic loads ----
    {
      const float* hprev =
          (t == 0) ? h0 : (hbuf + (size_t)((t - 1) & 1) * B * H);
#pragma unroll
      for (int i = 0; i < 8; ++i) {
        const int j = tid + (i << 8);        // 0..2047
        const int r = j >> 7;                // row 0..15
        const int cc = (j & 127) << 1;       // float col (even)
        unsigned long long* src = (unsigned long long*)(void*)
            (const_cast<float*>(hprev) + (size_t)(b0 + r) * H + cc);
        union { unsigned long long u; float2 f; } cv;
        cv.u = __hip_atomic_load(src, __ATOMIC_RELAXED,
                                 __HIP_MEMORY_SCOPE_AGENT);
        *(float2*)&hs_s[r][cc] = cv.f;
      }
    }
    __syncthreads();

    // ---- E: recurrent part (K=256, w_hh streamed from L1/L2) ----
#pragma unroll 4
    for (int k = 0; k < H; k += 4) {
      const float4 xv = *(const float4*)&hs_s[lb][k];
      const float4 w0 = *(const float4*)(hr0 + k);
      const float4 w1 = *(const float4*)(hr1 + k);
      const float4 w2 = *(const float4*)(hr2 + k);
      const float4 w3 = *(const float4*)(hr3 + k);
      acc0 = fmaf(xv.x, w0.x, fmaf(xv.y, w0.y, fmaf(xv.z, w0.z, fmaf(xv.w, w0.w, acc0))));
      acc1 = fmaf(xv.x, w1.x, fmaf(xv.y, w1.y, fmaf(xv.z, w1.z, fmaf(xv.w, w1.w, acc1))));
      acc2 = fmaf(xv.x, w2.x, fmaf(xv.y, w2.y, fmaf(xv.z, w2.z, fmaf(xv.w, w2.w, acc2))));
      acc3 = fmaf(xv.x, w3.x, fmaf(xv.y, w3.y, fmaf(xv.z, w3.z, fmaf(xv.w, w3.w, acc3))));
    }

    const float si = 1.f / (1.f + expf(-acc0));
    const float sf = 1.f / (1.f + expf(-acc1));
    const float tg = tanhf(acc2);
    const float so = 1.f / (1.f + expf(-acc3));
    const float cn = sf * c + si * tg;
    const float hn = so * tanhf(cn);
    c = cn;

    enc_out[((size_t)b * T + t) * H + n] = hn;
    __hip_atomic_store(hbuf + (size_t)(t & 1) * B * H + (size_t)b * H + n,
                       hn, __ATOMIC_RELAXED, __HIP_MEMORY_SCOPE_AGENT);
    __syncthreads();  // vmcnt(0): h stores ack'd at coherence point

    // ---- F: publish step completion (own line, no RMW, no fence) ----
    if (tid == 0) {
      __hip_atomic_store(myflag, (unsigned int)(t + 1), __ATOMIC_RELAXED,
                         __HIP_MEMORY_SCOPE_AGENT);
    }
  }
}

// ---------------------------------------------------------------------------
extern "C" void kernel_launch(void* const* d_in, const int* in_sizes, int n_in,
                              void* d_out, int out_size, void* d_ws, size_t ws_size,
                              hipStream_t stream) {
  (void)in_sizes; (void)n_in; (void)out_size; (void)ws_size;
  const float* x      = (const float*)d_in[0];
  const float* attn_w = (const float*)d_in[1];
  // d_in[2] (attn_b) provably cancels in the softmax -> unused
  const float* w_ih   = (const float*)d_in[3];
  const float* w_hh   = (const float*)d_in[4];
  const float* b_ih   = (const float*)d_in[5];
  const float* b_hh   = (const float*)d_in[6];
  const float* h0     = (const float*)d_in[7];
  const float* c0     = (const float*)d_in[8];

  float* out   = (float*)d_out;
  float* attns = out;                           // (B,T,F)
  float* enc   = out + (size_t)B * T * F;       // (B,T,H)

  unsigned int* flags = (unsigned int*)d_ws;    // 512 x 64 uints (128 KB)
  float* a_ws = (float*)d_ws + 512 * 64;        // (B,F)
  float* hbuf = a_ws + (size_t)B * F;           // (2,B,H)

  hipMemsetAsync(flags, 0, 512 * 64 * sizeof(unsigned int), stream);

  attn_softmax_kernel<<<dim3(B), dim3(128), 0, stream>>>(x, attn_w, a_ws, attns);

  void* args[] = { (void*)&x, (void*)&w_ih, (void*)&w_hh, (void*)&b_ih,
                   (void*)&b_hh, (void*)&h0, (void*)&c0, (void*)&a_ws,
                   (void*)&hbuf, (void*)&enc, (void*)&flags };
  hipError_t st = hipLaunchCooperativeKernel((void*)lstm_kernel, dim3(512),
                                             dim3(256), args, 0, stream);
  if (st != hipSuccess) {
    // coop rejection -> plain launch; kernel has no grid.sync and all 512 WGs
    // are co-resident at 24.5 KB LDS / 64 VGPR (>=6 blocks/CU by LDS).
    (void)hipGetLastError();  // clear sticky error
    lstm_kernel<<<dim3(512), dim3(256), 0, stream>>>(
        x, w_ih, w_hh, b_ih, b_hh, h0, c0, a_ws, hbuf, enc, flags);
  }
}